// Round 1
// 328.903 us; speedup vs baseline: 1.0316x; 1.0316x over previous
//
#include <hip/hip_runtime.h>

typedef __bf16 bf16;
typedef bf16 bf16x8 __attribute__((ext_vector_type(8)));
typedef bf16 bf16x4 __attribute__((ext_vector_type(4)));
typedef float f32x4 __attribute__((ext_vector_type(4)));

#define MFMA16(a, b, c) __builtin_amdgcn_mfma_f32_16x16x32_bf16((a), (b), (c), 0, 0, 0)

__device__ __forceinline__ void gload_lds16(const bf16* g, bf16* l) {
  __builtin_amdgcn_global_load_lds(
      (const __attribute__((address_space(1))) void*)g,
      (__attribute__((address_space(3))) void*)l, 16, 0, 0);
}

// ---------------------------------------------------------------------------
// fp32 -> bf16 convert
// ---------------------------------------------------------------------------
__global__ __launch_bounds__(256) void cvt_f32_bf16(const float* __restrict__ src,
                                                    bf16* __restrict__ dst, int n4) {
  int i = blockIdx.x * blockDim.x + threadIdx.x;
  if (i < n4) {
    float4 v = ((const float4*)src)[i];
    bf16x4 o;
    o[0] = (bf16)v.x; o[1] = (bf16)v.y; o[2] = (bf16)v.z; o[3] = (bf16)v.w;
    ((bf16x4*)dst)[i] = o;
  }
}

// ---------------------------------------------------------------------------
// GEMM C = A * B^T (m97 structure — kept for the output projection)
// ---------------------------------------------------------------------------
template <typename OutT>
__global__ __launch_bounds__(256) void gemm_bt(const bf16* __restrict__ A,
                                               const bf16* __restrict__ B,
                                               OutT* __restrict__ C,
                                               int M, int N, int K) {
  __shared__ __align__(16) bf16 As[128 * 64];
  __shared__ __align__(16) bf16 Bs[128 * 64];
  const int tid = threadIdx.x;
  const int w = tid >> 6, lane = tid & 63;
  const int l15 = lane & 15, quad = lane >> 4;
  const int m0 = blockIdx.y * 128, n0 = blockIdx.x * 128;
  const int wm = (w >> 1) * 64, wn = (w & 1) * 64;

  f32x4 acc[4][4] = {};

  for (int k0 = 0; k0 < K; k0 += 64) {
#pragma unroll
    for (int i = 0; i < 4; i++) {
      int s = w * 256 + i * 64 + lane;
      int row = s >> 3;
      int c8 = (s & 7) ^ (row & 7);
      gload_lds16(A + (size_t)(m0 + row) * K + k0 + c8 * 8, As + (w * 256 + i * 64) * 8);
    }
#pragma unroll
    for (int i = 0; i < 4; i++) {
      int s = w * 256 + i * 64 + lane;
      int row = s >> 3;
      int c8 = (s & 7) ^ (row & 7);
      gload_lds16(B + (size_t)(n0 + row) * K + k0 + c8 * 8, Bs + (w * 256 + i * 64) * 8);
    }
    __syncthreads();

#pragma unroll
    for (int kk = 0; kk < 2; kk++) {
      bf16x8 af[4], bfr[4];
#pragma unroll
      for (int mt = 0; mt < 4; mt++) {
        int row = wm + mt * 16 + l15;
        int slot = row * 8 + ((kk * 4 + quad) ^ (row & 7));
        af[mt] = *(const bf16x8*)(As + slot * 8);
      }
#pragma unroll
      for (int nt = 0; nt < 4; nt++) {
        int row = wn + nt * 16 + l15;
        int slot = row * 8 + ((kk * 4 + quad) ^ (row & 7));
        bfr[nt] = *(const bf16x8*)(Bs + slot * 8);
      }
#pragma unroll
      for (int mt = 0; mt < 4; mt++)
#pragma unroll
        for (int nt = 0; nt < 4; nt++)
          acc[mt][nt] = MFMA16(af[mt], bfr[nt], acc[mt][nt]);
    }
    __syncthreads();
  }

#pragma unroll
  for (int mt = 0; mt < 4; mt++)
#pragma unroll
    for (int nt = 0; nt < 4; nt++) {
      int row = m0 + wm + mt * 16 + quad * 4;
      int col = n0 + wn + nt * 16 + l15;
#pragma unroll
      for (int r = 0; r < 4; r++)
        C[(size_t)(row + r) * N + col] = (OutT)acc[mt][nt][r];
    }
}

// ---------------------------------------------------------------------------
// 256x256-tile pipelined GEMM C = A*B^T, bf16 out. BK=32, 4-slot LDS ring,
// distance-2 prefetch, counted vmcnt(4) (never 0 in steady state), 2 phases
// per K-tile with 16 MFMA each, setprio around MFMA.
//
// Schedule invariants (proof sketch):
//  - tile t is read from slot t&3; tile t+2 is staged into slot (t+2)&3,
//    whose last reads were in tile t-2, drained (lgkmcnt) before the
//    end-of-(t-2) barrier -> WAR safe.
//  - 4 gload_lds per thread per tile, FIFO; end-of-tile vmcnt(4) leaves only
//    tile t+2's 4 loads in flight => tile t+1 fully landed before its reads.
//  - every wave executes vmcnt before the shared barrier, so cross-wave
//    visibility of staged data is established at the barrier.
// Requires M%256==0, N%256==0, K%32==0, K/32>=2, gridDim.x==(M/256)*(N/256).
// ---------------------------------------------------------------------------
__global__ __launch_bounds__(512, 2) void gemm256_bt(const bf16* __restrict__ A,
                                                     const bf16* __restrict__ B,
                                                     bf16* __restrict__ C,
                                                     int M, int N, int K) {
  __shared__ __align__(16) bf16 SA[4][8192];   // 4 slots x (256 rows x 32 k)
  __shared__ __align__(16) bf16 SB[4][8192];
  const int NT = K >> 5;
  const int tid = threadIdx.x;
  const int w = tid >> 6, lane = tid & 63;
  const int l15 = lane & 15, quad = lane >> 4;
  const int wr = w >> 2, wc = w & 3;

  // XCD-chunked bijective block swizzle (nwg % 8 == 0)
  const int nbx = N >> 8;
  const int nwg = (M >> 8) * nbx;
  const int wg = ((int)blockIdx.x & 7) * (nwg >> 3) + ((int)blockIdx.x >> 3);
  const int bm0 = (wg / nbx) << 8;
  const int bn0 = (wg % nbx) << 8;

  // Staging decode: phys slot s=tid -> (row, granule) with involution
  // p = u ^ (q&7), u = (row&1)*4 + g, row = 2q + (u>>2). LDS dest is linear.
  const int q = tid >> 3, p = tid & 7;
  const int u = p ^ (q & 7);
  const int srow = 2 * q + (u >> 2);   // 0..127 within half-tile
  const int sg = u & 3;                // 8-elt k-granule
  const bf16* sA0 = A + (size_t)(bm0 + srow) * K + sg * 8;
  const bf16* sA1 = sA0 + (size_t)128 * K;
  const bf16* sB0 = B + (size_t)(bn0 + srow) * K + sg * 8;
  const bf16* sB1 = sB0 + (size_t)128 * K;
  const int dst = w * 512;             // wave-uniform LDS offset (elements)

  // Fragment read offsets: same involution on the read side.
  // p depends only on the lane -> constant across mt/nt.
  const int pA = (((l15 & 1) << 2) + quad) ^ (l15 >> 1);
  const int aoff = wr * 4096 + (l15 >> 1) * 64 + pA * 8;
  const int boff = (wc >> 1) * 4096 + (wc & 1) * 2048 + (l15 >> 1) * 64 + pA * 8;

  f32x4 acc[8][4] = {};

  // Prologue: stage tiles 0 and 1 (8 loads), wait tile 0 (vmcnt(4)).
#pragma unroll
  for (int tt = 0; tt < 2; ++tt) {
    gload_lds16(sA0 + tt * 32, &SA[tt][0] + dst);
    gload_lds16(sA1 + tt * 32, &SA[tt][4096] + dst);
    gload_lds16(sB0 + tt * 32, &SB[tt][0] + dst);
    gload_lds16(sB1 + tt * 32, &SB[tt][4096] + dst);
  }
  asm volatile("s_waitcnt vmcnt(4)" ::: "memory");
  __builtin_amdgcn_sched_barrier(0);
  __builtin_amdgcn_s_barrier();
  __builtin_amdgcn_sched_barrier(0);

  for (int t = 0; t < NT; ++t) {
    const bf16* sa = &SA[t & 3][0];
    const bf16* sb = &SB[t & 3][0];
    const int ts = t + 2;
    const int sl = ts & 3;

    // ---- phase 1: read B(all) + A(rows 0..63); stage A-halves of t+2
    bf16x8 bfr[4], af[4];
#pragma unroll
    for (int nt = 0; nt < 4; ++nt) bfr[nt] = *(const bf16x8*)(sb + boff + nt * 512);
#pragma unroll
    for (int mt = 0; mt < 4; ++mt) af[mt] = *(const bf16x8*)(sa + aoff + mt * 512);
    if (ts < NT) {
      gload_lds16(sA0 + ts * 32, &SA[sl][0] + dst);
      gload_lds16(sA1 + ts * 32, &SA[sl][4096] + dst);
    }
    __builtin_amdgcn_sched_barrier(0);
    __builtin_amdgcn_s_barrier();
    asm volatile("s_waitcnt lgkmcnt(0)" ::: "memory");
    __builtin_amdgcn_sched_barrier(0);
    __builtin_amdgcn_s_setprio(1);
#pragma unroll
    for (int mt = 0; mt < 4; ++mt)
#pragma unroll
      for (int nt = 0; nt < 4; ++nt)
        acc[mt][nt] = MFMA16(af[mt], bfr[nt], acc[mt][nt]);
    __builtin_amdgcn_s_setprio(0);
    __builtin_amdgcn_sched_barrier(0);
    __builtin_amdgcn_s_barrier();
    __builtin_amdgcn_sched_barrier(0);

    // ---- phase 2: read A(rows 64..127); stage B-halves of t+2
#pragma unroll
    for (int mt = 0; mt < 4; ++mt) af[mt] = *(const bf16x8*)(sa + aoff + (mt + 4) * 512);
    if (ts < NT) {
      gload_lds16(sB0 + ts * 32, &SB[sl][0] + dst);
      gload_lds16(sB1 + ts * 32, &SB[sl][4096] + dst);
    }
    __builtin_amdgcn_sched_barrier(0);
    __builtin_amdgcn_s_barrier();
    asm volatile("s_waitcnt lgkmcnt(0)" ::: "memory");
    __builtin_amdgcn_sched_barrier(0);
    __builtin_amdgcn_s_setprio(1);
#pragma unroll
    for (int mt = 0; mt < 4; ++mt)
#pragma unroll
      for (int nt = 0; nt < 4; ++nt)
        acc[mt + 4][nt] = MFMA16(af[mt], bfr[nt], acc[mt + 4][nt]);
    __builtin_amdgcn_s_setprio(0);
    if (ts < NT) {
      asm volatile("s_waitcnt vmcnt(4)" ::: "memory");  // tile t+1 landed; t+2 in flight
    } else {
      asm volatile("s_waitcnt vmcnt(0)" ::: "memory");  // epilogue drain
    }
    __builtin_amdgcn_sched_barrier(0);
    __builtin_amdgcn_s_barrier();
    __builtin_amdgcn_sched_barrier(0);
  }

  // C write
#pragma unroll
  for (int mt = 0; mt < 8; ++mt)
#pragma unroll
    for (int nt = 0; nt < 4; ++nt) {
      int row = bm0 + wr * 128 + mt * 16 + quad * 4;
      int col = bn0 + wc * 64 + nt * 16 + l15;
#pragma unroll
      for (int r = 0; r < 4; ++r)
        C[(size_t)(row + r) * N + col] = (bf16)acc[mt][nt][r];
    }
}

// ---------------------------------------------------------------------------
// RMSNorm + RoPE. Q prescaled by D^-0.5 * log2(e) for fixed-max exp2 softmax
// (|score*log2e| <= 11.32*1.4427 < 17.3 by RMSNorm bound; M = 12*log2(e)).
// ---------------------------------------------------------------------------
__global__ __launch_bounds__(256) void normrope(const bf16* __restrict__ QKVb,
                                                const float* __restrict__ cosb,
                                                const float* __restrict__ sinb,
                                                const float* __restrict__ qw,
                                                const float* __restrict__ kw,
                                                bf16* __restrict__ Qb,
                                                bf16* __restrict__ Kb) {
  const int wid = (blockIdx.x * blockDim.x + threadIdx.x) >> 6;
  const int lane = threadIdx.x & 63;
  const int s = wid / 24;
  const int h = wid % 24;
  const bool isq = (h < 16);
  const int col0 = isq ? h * 128 : 2048 + (h - 16) * 128;
  const float* wt = isq ? qw : kw;

  const bf16* row = QKVb + (size_t)s * 4096 + col0;
  float x1 = (float)row[lane];
  float x2 = (float)row[lane + 64];

  float ss = x1 * x1 + x2 * x2;
#pragma unroll
  for (int m = 32; m >= 1; m >>= 1) ss += __shfl_xor(ss, m, 64);
  float rs = rsqrtf(ss * (1.0f / 128.0f) + 1e-6f);

  float c = cosb[(size_t)s * 128 + lane];
  float sn = sinb[(size_t)s * 128 + lane];
  float xn1 = x1 * rs * wt[lane];
  float xn2 = x2 * rs * wt[lane + 64];
  float o1 = xn1 * c - xn2 * sn;
  float o2 = xn2 * c + xn1 * sn;
  const float scale = isq ? 0.12751652f : 1.0f;  // D^-0.5 * log2(e)
  o1 *= scale; o2 *= scale;

  bf16* dst = isq ? (Qb + ((size_t)h * 4096 + s) * 128)
                  : (Kb + ((size_t)(h - 16) * 4096 + s) * 128);
  dst[lane] = (bf16)o1;
  dst[lane + 64] = (bf16)o2;
}

// ---------------------------------------------------------------------------
// V transpose + in-tile permute: Vtp[kvh][d][t*64 + kp] = V[t*64 + sig(kp)][d]
// with sig(kp) = (kp&3)*16 + (kp>>2). Matches attention's P layout kp=l15*4+c.
// ---------------------------------------------------------------------------
__global__ __launch_bounds__(256) void vtrans(const bf16* __restrict__ QKVb,
                                              bf16* __restrict__ Vtp) {
  __shared__ __align__(16) bf16 T[64 * 136];
  const int kvh = blockIdx.y;
  const int s0 = blockIdx.x * 64;   // one 64-key tile
  const int tid = threadIdx.x;
  for (int g = tid; g < 1024; g += 256) {
    int s = g >> 4, cg = g & 15;
    *(bf16x8*)(T + s * 136 + cg * 8) =
        *(const bf16x8*)(QKVb + (size_t)(s0 + s) * 4096 + 3072 + kvh * 128 + cg * 8);
  }
  __syncthreads();
  for (int g = tid; g < 1024; g += 256) {
    int d = g >> 3, sg = g & 7;
    bf16x8 v;
#pragma unroll
    for (int j = 0; j < 8; j++) {
      int kp = sg * 8 + j;
      int s = (kp & 3) * 16 + (kp >> 2);
      v[j] = T[s * 136 + d];
    }
    *(bf16x8*)(Vtp + ((size_t)kvh * 128 + d) * 4096 + s0 + sg * 8) = v;
  }
}

// ---------------------------------------------------------------------------
// Sliding-window GQA flash attention (unchanged this round).
// ---------------------------------------------------------------------------
__global__ __launch_bounds__(256, 2) void attn_kernel(const bf16* __restrict__ Qb,
                                                      const bf16* __restrict__ Kb,
                                                      const bf16* __restrict__ Vtp,
                                                      bf16* __restrict__ Ob) {
  const int SEQ = 4096, W = 1024;
  const float MP = 17.312340f;  // 12 * log2(e)
  __shared__ __align__(16) bf16 Ks[64 * 128];    // [key][d granule xor-swizzled]
  __shared__ __align__(16) bf16 Vs[128 * 64];    // [d][kp granule xor-swizzled]
  __shared__ __align__(16) bf16 Ps[4][32 * 64];  // per-wave P, xor-swizzled

  const int id = blockIdx.x;
  const int kvh = id & 7, gq = (id >> 3) & 1, h = kvh * 2 + gq;
  const int qb0 = (id >> 4) * 128;
  const int tid = threadIdx.x, w = tid >> 6, lane = tid & 63;
  const int l15 = lane & 15, quad = lane >> 4;
  const int qw0 = qb0 + w * 32;

  bf16x8 qf[2][4];
#pragma unroll
  for (int m = 0; m < 2; m++) {
    const bf16* qp = Qb + ((size_t)h * SEQ + qw0 + m * 16 + l15) * 128 + quad * 8;
#pragma unroll
    for (int kb = 0; kb < 4; kb++) qf[m][kb] = *(const bf16x8*)(qp + kb * 32);
  }

  f32x4 o[2][8] = {};
  f32x4 lr[2] = {};
  bf16* pw = &Ps[w][0];
  const bf16* kbase = Kb + (size_t)kvh * SEQ * 128;
  const bf16* vbase = Vtp + (size_t)kvh * 128 * SEQ;

  int jmin = qb0 - (W - 1); if (jmin < 0) jmin = 0;
  const int kt0 = jmin >> 6, kt1 = (qb0 + 127) >> 6;

  for (int kt = kt0; kt <= kt1; ++kt) {
    const int k0 = kt * 64;
#pragma unroll
    for (int i = 0; i < 4; i++) {
      int slot = w * 256 + i * 64 + lane;
      int key = slot >> 4, gg = slot & 15;
      int gsw = gg ^ (key & 7);
      gload_lds16(kbase + (size_t)(k0 + key) * 128 + gsw * 8, Ks + (w * 256 + i * 64) * 8);
    }
#pragma unroll
    for (int i = 0; i < 4; i++) {
      int slot = w * 256 + i * 64 + lane;
      int d = slot >> 3, gg = slot & 7;
      int gsw = gg ^ (d & 7);
      gload_lds16(vbase + (size_t)d * SEQ + k0 + gsw * 8, Vs + (w * 256 + i * 64) * 8);
    }
    __syncthreads();

    const bool alive = (k0 <= qw0 + 31) && (k0 + 63 > qw0 - W);
    if (alive) {
      const bool full = (k0 + 63 <= qw0) && (k0 > qw0 + 31 - W);
      f32x4 s[2][4] = {};
#pragma unroll
      for (int c = 0; c < 4; c++) {
        const int key = c * 16 + l15;
        bf16x8 kf[4];
#pragma unroll
        for (int kb = 0; kb < 4; kb++)
          kf[kb] = *(const bf16x8*)(Ks + key * 128 + (((kb * 4 + quad) ^ (key & 7)) << 3));
#pragma unroll
        for (int kb = 0; kb < 4; kb++) {
          s[0][c] = MFMA16(qf[0][kb], kf[kb], s[0][c]);
          s[1][c] = MFMA16(qf[1][kb], kf[kb], s[1][c]);
        }
      }
#pragma unroll
      for (int m = 0; m < 2; m++)
#pragma unroll
        for (int r = 0; r < 4; r++) {
          float p[4];
          if (full) {
#pragma unroll
            for (int c = 0; c < 4; c++) p[c] = __builtin_amdgcn_exp2f(s[m][c][r] - MP);
          } else {
            const int i_ = qw0 + m * 16 + quad * 4 + r;
#pragma unroll
            for (int c = 0; c < 4; c++) {
              int j = k0 + c * 16 + l15;
              p[c] = (j <= i_ && j > i_ - W) ? __builtin_amdgcn_exp2f(s[m][c][r] - MP) : 0.0f;
            }
          }
          lr[m][r] += p[0] + p[1] + p[2] + p[3];
          bf16x4 pk;
          pk[0] = (bf16)p[0]; pk[1] = (bf16)p[1]; pk[2] = (bf16)p[2]; pk[3] = (bf16)p[3];
          const int qrow = m * 16 + quad * 4 + r;
          *(bf16x4*)(pw + qrow * 64 + (((l15 >> 1) ^ (qrow & 7)) << 3) + (l15 & 1) * 4) = pk;
        }
      asm volatile("s_waitcnt lgkmcnt(0)" ::: "memory");
      bf16x8 pf[2][2];
#pragma unroll
      for (int m = 0; m < 2; m++)
#pragma unroll
        for (int kb = 0; kb < 2; kb++)
          pf[m][kb] = *(const bf16x8*)(pw + (m * 16 + l15) * 64 +
                                       (((kb * 4 + quad) ^ (l15 & 7)) << 3));
#pragma unroll
      for (int n = 0; n < 8; n++) {
        const int d = n * 16 + l15;
        bf16x8 vf0 = *(const bf16x8*)(Vs + d * 64 + ((quad ^ (l15 & 7)) << 3));
        bf16x8 vf1 = *(const bf16x8*)(Vs + d * 64 + (((4 + quad) ^ (l15 & 7)) << 3));
        o[0][n] = MFMA16(pf[0][0], vf0, o[0][n]);
        o[0][n] = MFMA16(pf[0][1], vf1, o[0][n]);
        o[1][n] = MFMA16(pf[1][0], vf0, o[1][n]);
        o[1][n] = MFMA16(pf[1][1], vf1, o[1][n]);
      }
    }
    __syncthreads();
  }

  float linv[2][4];
#pragma unroll
  for (int m = 0; m < 2; m++)
#pragma unroll
    for (int r = 0; r < 4; r++) {
      float v = lr[m][r];
      v += __shfl_xor(v, 1, 64);
      v += __shfl_xor(v, 2, 64);
      v += __shfl_xor(v, 4, 64);
      v += __shfl_xor(v, 8, 64);
      linv[m][r] = 1.0f / v;
    }
#pragma unroll
  for (int m = 0; m < 2; m++)
#pragma unroll
    for (int n = 0; n < 8; n++)
#pragma unroll
      for (int r = 0; r < 4; r++) {
        int i_ = qw0 + m * 16 + quad * 4 + r;
        Ob[(size_t)i_ * 2048 + h * 128 + n * 16 + l15] = (bf16)(o[m][n][r] * linv[m][r]);
      }
}

// ---------------------------------------------------------------------------
// Orchestration
// ---------------------------------------------------------------------------
extern "C" void kernel_launch(void* const* d_in, const int* in_sizes, int n_in,
                              void* d_out, int out_size, void* d_ws, size_t ws_size,
                              hipStream_t stream) {
  const float* hid  = (const float*)d_in[0];
  const float* cosb = (const float*)d_in[1];
  const float* sinb = (const float*)d_in[2];
  const float* Wq   = (const float*)d_in[3];
  const float* Wk   = (const float*)d_in[4];
  const float* Wv   = (const float*)d_in[5];
  const float* Wo   = (const float*)d_in[6];
  const float* qw   = (const float*)d_in[7];
  const float* kw   = (const float*)d_in[8];

  if (ws_size < (size_t)(112u) * 1024u * 1024u) return;

  char* ws = (char*)d_ws;
  bf16* Xbf  = (bf16*)(ws);                         // 4096x2048 (16 MB); slot
  bf16* Vtp  = (bf16*)(ws);                         //   reused for Vtp after gemm1
  bf16* Wcat = (bf16*)(ws + (16u << 20));           // [Wq;Wk;Wv] 4096x2048
  bf16* Wob  = (bf16*)(ws + (32u << 20));           // 2048x2048 (8 MB)
  bf16* QKVb = (bf16*)(ws + (40u << 20));           // 4096x4096 (32 MB)
  bf16* Qb   = (bf16*)(ws + (72u << 20));           // [16][4096][128] (16 MB)
  bf16* Kb   = (bf16*)(ws + (88u << 20));           // [8][4096][128] (8 MB)
  bf16* Ob   = (bf16*)(ws + (96u << 20));           // 4096x2048 (16 MB)

  cvt_f32_bf16<<<8192, 256, 0, stream>>>(hid, Xbf, 2097152);
  cvt_f32_bf16<<<4096, 256, 0, stream>>>(Wq, Wcat, 1048576);
  cvt_f32_bf16<<<2048, 256, 0, stream>>>(Wk, Wcat + 4194304, 524288);
  cvt_f32_bf16<<<2048, 256, 0, stream>>>(Wv, Wcat + 6291456, 524288);
  cvt_f32_bf16<<<4096, 256, 0, stream>>>(Wo, Wob, 1048576);

  gemm256_bt<<<256, 512, 0, stream>>>(Xbf, Wcat, QKVb, 4096, 4096, 2048);
  vtrans<<<dim3(64, 8), 256, 0, stream>>>(QKVb, Vtp);   // Xbf dead after gemm1
  normrope<<<24576, 256, 0, stream>>>(QKVb, cosb, sinb, qw, kw, Qb, Kb);
  attn_kernel<<<512, 256, 0, stream>>>(Qb, Kb, Vtp, Ob);
  gemm_bt<float><<<dim3(16, 32), 256, 0, stream>>>(Ob, Wob, (float*)d_out, 4096, 2048, 2048);
}

// Round 2
// 325.396 us; speedup vs baseline: 1.0428x; 1.0108x over previous
//
#include <hip/hip_runtime.h>

typedef __bf16 bf16;
typedef bf16 bf16x8 __attribute__((ext_vector_type(8)));
typedef bf16 bf16x4 __attribute__((ext_vector_type(4)));
typedef float f32x4 __attribute__((ext_vector_type(4)));

#define MFMA16(a, b, c) __builtin_amdgcn_mfma_f32_16x16x32_bf16((a), (b), (c), 0, 0, 0)

__device__ __forceinline__ void gload_lds16(const bf16* g, bf16* l) {
  __builtin_amdgcn_global_load_lds(
      (const __attribute__((address_space(1))) void*)g,
      (__attribute__((address_space(3))) void*)l, 16, 0, 0);
}

template <int N>
__device__ __forceinline__ void lgkm_fence() {
  if constexpr (N == 0) asm volatile("s_waitcnt lgkmcnt(0)" ::: "memory");
  else if constexpr (N == 4) asm volatile("s_waitcnt lgkmcnt(4)" ::: "memory");
  else if constexpr (N == 8) asm volatile("s_waitcnt lgkmcnt(8)" ::: "memory");
  else if constexpr (N == 12) asm volatile("s_waitcnt lgkmcnt(12)" ::: "memory");
  __builtin_amdgcn_sched_barrier(0);
}
__device__ __forceinline__ void bar_fence() {
  __builtin_amdgcn_sched_barrier(0);
  __builtin_amdgcn_s_barrier();
}

// ---------------------------------------------------------------------------
// fp32 -> bf16 convert
// ---------------------------------------------------------------------------
__global__ __launch_bounds__(256) void cvt_f32_bf16(const float* __restrict__ src,
                                                    bf16* __restrict__ dst, int n4) {
  int i = blockIdx.x * blockDim.x + threadIdx.x;
  if (i < n4) {
    float4 v = ((const float4*)src)[i];
    bf16x4 o;
    o[0] = (bf16)v.x; o[1] = (bf16)v.y; o[2] = (bf16)v.z; o[3] = (bf16)v.w;
    ((bf16x4*)dst)[i] = o;
  }
}

// ---------------------------------------------------------------------------
// Pipelined GEMM C = A * B^T. BK=64, 2-slot LDS dbuf, 4 quadrant-phases/tile.
// Key schedule property: phase P_k issues the ds_reads for phase P_{k+1}'s
// MFMA operands, and waits with a COUNTED lgkmcnt that only drains the reads
// issued in P_{k-1} (a full phase old -> ~0 stall). So LDS read service
// overlaps the MFMA cluster instead of serializing before it.
//
// Per tile t (slot s = t&1, o = s^1), quadrants of the wave tile:
//   Q1=(m0,n0) Q2=(m0,n1) Q3=(m1,n1) Q4=(m1,n0)
//   P1: reads Bq1(t)        | bar | lgkm(NTT) | stage ALL of t+1 -> o | MFMA Q1
//   P2: reads Aq1(t)        | bar | lgkm(MT)  |                        MFMA Q2
//   P3: reads Bq0re(t)      | vmcnt(0) (t+1 loads, >=2 phases old)
//                           | bar (publication of slot o) | lgkm(NTT) | MFMA Q3
//   P4: reads Aq0,Bq0 (t+1) | bar | lgkm(MT+NTT) |                    MFMA Q4
// WAR safety: staging in P1's MFMA slot overwrites regions whose last
// consumer-read lgkm is in tile t-1 (>=1 barrier earlier). Publication:
// vmcnt(0) + barrier at P3 precedes the first read-issue of t+1 (P4 top).
// Requires M%BM==0, N%BN==0, K%128==0, grid = (M/BM)*(N/BN), 512 threads.
// ---------------------------------------------------------------------------
template <int BM, int BN, int MT, int NTT, typename OutT>
__global__ __launch_bounds__(512, 2) void gemm_pipe(const bf16* __restrict__ A,
                                                    const bf16* __restrict__ B,
                                                    OutT* __restrict__ C,
                                                    int M, int N, int K) {
  constexpr int MH = MT / 2, NH = NTT / 2;
  constexpr int ASLOT = BM * 64;           // elements per A slot
  constexpr int BSLOT = BN * 64;
  constexpr int NLA = BM / 64, NLB = BN / 64;
  __shared__ __align__(16) bf16 SA[2 * ASLOT];
  __shared__ __align__(16) bf16 SB[2 * BSLOT];

  const int NTILES = K >> 6;
  const int tid = threadIdx.x;
  const int w = tid >> 6, lane = tid & 63;
  const int l15 = lane & 15, quad = lane >> 4;
  const int wr = w >> 2, wc = w & 3;       // 2 x 4 waves

  // XCD-chunked bijective block swizzle (nwg % 8 == 0)
  const int nbx = N / BN;
  const int nwg = (M / BM) * nbx;
  const int wg = ((int)blockIdx.x & 7) * (nwg >> 3) + ((int)blockIdx.x >> 3);
  const int bm0 = (wg / nbx) * BM;
  const int bn0 = (wg % nbx) * BN;

  // Staging: thread -> LDS slot (tid + i*512); slot = row*8 + p,
  // stored granule = p ^ (row&7) (involution, conflict-free reads).
  const int r0 = tid >> 3;
  const int sg = (tid & 7) ^ ((tid >> 3) & 7);
  unsigned aoffg[NLA], boffg[NLB];
#pragma unroll
  for (int i = 0; i < NLA; ++i)
    aoffg[i] = (unsigned)((bm0 + r0 + i * 64) * K + sg * 8);
#pragma unroll
  for (int i = 0; i < NLB; ++i)
    boffg[i] = (unsigned)((bn0 + r0 + i * 64) * K + sg * 8);

  // Fragment read byte offsets: row*128 + p(kk)*16, p = (kk*4+quad)^(l15&7).
  const int xl = l15 & 7;
  const int p0 = quad ^ xl;
  const int baseA0 = (wr * (MT * 16) + l15) * 128 + p0 * 16;
  const int baseA1 = (wr * (MT * 16) + l15) * 128 + ((p0 ^ 4) * 16);
  const int baseB0 = (wc * (NTT * 16) + l15) * 128 + p0 * 16;
  const int baseB1 = (wc * (NTT * 16) + l15) * 128 + ((p0 ^ 4) * 16);
  const char* saB = (const char*)&SA[0];
  const char* sbB = (const char*)&SB[0];

  f32x4 acc[MT][NTT] = {};
  bf16x8 As[2][MH][2];   // set0 = Aq0 (rows half 0), set1 = Aq1
  bf16x8 Bs[2][NH][2];   // sets alternate with tile parity

#define LDA_(SL, H, DST)                                                        \
  _Pragma("unroll") for (int mt = 0; mt < MH; ++mt) {                           \
    (DST)[mt][0] = *(const bf16x8*)(saB + (SL) * (ASLOT * 2) + baseA0 +         \
                                    ((H) * MH + mt) * 2048);                    \
    (DST)[mt][1] = *(const bf16x8*)(saB + (SL) * (ASLOT * 2) + baseA1 +         \
                                    ((H) * MH + mt) * 2048);                    \
  }
#define LDB_(SL, G, DST)                                                        \
  _Pragma("unroll") for (int nt = 0; nt < NH; ++nt) {                           \
    (DST)[nt][0] = *(const bf16x8*)(sbB + (SL) * (BSLOT * 2) + baseB0 +         \
                                    ((G) * NH + nt) * 2048);                    \
    (DST)[nt][1] = *(const bf16x8*)(sbB + (SL) * (BSLOT * 2) + baseB1 +         \
                                    ((G) * NH + nt) * 2048);                    \
  }
#define QMFMA_(AS, BS, MHI, NHI)                                                \
  __builtin_amdgcn_s_setprio(1);                                                \
  _Pragma("unroll") for (int mt = 0; mt < MH; ++mt)                             \
      _Pragma("unroll") for (int nt = 0; nt < NH; ++nt) {                       \
    acc[(MHI) * MH + mt][(NHI) * NH + nt] = MFMA16(                             \
        (AS)[mt][0], (BS)[nt][0], acc[(MHI) * MH + mt][(NHI) * NH + nt]);       \
    acc[(MHI) * MH + mt][(NHI) * NH + nt] = MFMA16(                             \
        (AS)[mt][1], (BS)[nt][1], acc[(MHI) * MH + mt][(NHI) * NH + nt]);       \
  }                                                                             \
  __builtin_amdgcn_s_setprio(0);
#define STAGE_(SO, TS)                                                          \
  _Pragma("unroll") for (int i = 0; i < NLA; ++i)                               \
      gload_lds16(A + aoffg[i] + (TS) * 64, SA + (SO) * ASLOT + tid * 8 + i * 4096); \
  _Pragma("unroll") for (int i = 0; i < NLB; ++i)                               \
      gload_lds16(B + boffg[i] + (TS) * 64, SB + (SO) * BSLOT + tid * 8 + i * 4096);

#define GTILE_BODY(PAR, TS)                                                     \
  {                                                                             \
    constexpr int sl_ = (PAR), so_ = (PAR) ^ 1;                                 \
    constexpr int e0_ = (PAR), e1_ = (PAR) ^ 1;                                 \
    /* P1 */                                                                    \
    LDB_(sl_, 1, Bs[e1_]);                                                      \
    bar_fence();                                                                \
    lgkm_fence<NTT>();                                                          \
    if ((TS) < NTILES) { STAGE_(so_, (TS)); }                                   \
    QMFMA_(As[0], Bs[e0_], 0, 0);                                               \
    /* P2 */                                                                    \
    LDA_(sl_, 1, As[1]);                                                        \
    bar_fence();                                                                \
    lgkm_fence<MT>();                                                           \
    QMFMA_(As[0], Bs[e1_], 0, 1);                                               \
    /* P3 */                                                                    \
    LDB_(sl_, 0, Bs[e0_]);                                                      \
    asm volatile("s_waitcnt vmcnt(0)" ::: "memory");                            \
    bar_fence();                                                                \
    lgkm_fence<NTT>();                                                          \
    QMFMA_(As[1], Bs[e1_], 1, 1);                                               \
    /* P4 */                                                                    \
    LDA_(so_, 0, As[0]);                                                        \
    LDB_(so_, 0, Bs[e1_]);                                                      \
    bar_fence();                                                                \
    lgkm_fence<MT + NTT>();                                                     \
    QMFMA_(As[1], Bs[e0_], 1, 0);                                               \
  }

  // Prologue: stage tile 0, publish, pre-read Q1(0) operands.
  { STAGE_(0, 0); }
  asm volatile("s_waitcnt vmcnt(0)" ::: "memory");
  bar_fence();
  __builtin_amdgcn_sched_barrier(0);
  LDA_(0, 0, As[0]);
  LDB_(0, 0, Bs[0]);

  for (int t = 0; t < NTILES; t += 2) {
    GTILE_BODY(0, t + 1);
    GTILE_BODY(1, t + 2);
  }

#undef LDA_
#undef LDB_
#undef QMFMA_
#undef STAGE_
#undef GTILE_BODY

  // C write
#pragma unroll
  for (int mt = 0; mt < MT; ++mt)
#pragma unroll
    for (int nt = 0; nt < NTT; ++nt) {
      int row = bm0 + wr * (MT * 16) + mt * 16 + quad * 4;
      int col = bn0 + wc * (NTT * 16) + nt * 16 + l15;
#pragma unroll
      for (int r = 0; r < 4; ++r)
        C[(size_t)(row + r) * N + col] = (OutT)acc[mt][nt][r];
    }
}

// ---------------------------------------------------------------------------
// RMSNorm + RoPE. Q prescaled by D^-0.5 * log2(e) for fixed-max exp2 softmax
// (|score*log2e| <= 11.32*1.4427 < 17.3 by RMSNorm bound; M = 12*log2(e)).
// ---------------------------------------------------------------------------
__global__ __launch_bounds__(256) void normrope(const bf16* __restrict__ QKVb,
                                                const float* __restrict__ cosb,
                                                const float* __restrict__ sinb,
                                                const float* __restrict__ qw,
                                                const float* __restrict__ kw,
                                                bf16* __restrict__ Qb,
                                                bf16* __restrict__ Kb) {
  const int wid = (blockIdx.x * blockDim.x + threadIdx.x) >> 6;
  const int lane = threadIdx.x & 63;
  const int s = wid / 24;
  const int h = wid % 24;
  const bool isq = (h < 16);
  const int col0 = isq ? h * 128 : 2048 + (h - 16) * 128;
  const float* wt = isq ? qw : kw;

  const bf16* row = QKVb + (size_t)s * 4096 + col0;
  float x1 = (float)row[lane];
  float x2 = (float)row[lane + 64];

  float ss = x1 * x1 + x2 * x2;
#pragma unroll
  for (int m = 32; m >= 1; m >>= 1) ss += __shfl_xor(ss, m, 64);
  float rs = rsqrtf(ss * (1.0f / 128.0f) + 1e-6f);

  float c = cosb[(size_t)s * 128 + lane];
  float sn = sinb[(size_t)s * 128 + lane];
  float xn1 = x1 * rs * wt[lane];
  float xn2 = x2 * rs * wt[lane + 64];
  float o1 = xn1 * c - xn2 * sn;
  float o2 = xn2 * c + xn1 * sn;
  const float scale = isq ? 0.12751652f : 1.0f;  // D^-0.5 * log2(e)
  o1 *= scale; o2 *= scale;

  bf16* dst = isq ? (Qb + ((size_t)h * 4096 + s) * 128)
                  : (Kb + ((size_t)(h - 16) * 4096 + s) * 128);
  dst[lane] = (bf16)o1;
  dst[lane + 64] = (bf16)o2;
}

// ---------------------------------------------------------------------------
// V transpose + in-tile permute: Vtp[kvh][d][t*64 + kp] = V[t*64 + sig(kp)][d]
// with sig(kp) = (kp&3)*16 + (kp>>2). Matches attention's P layout kp=l15*4+c.
// ---------------------------------------------------------------------------
__global__ __launch_bounds__(256) void vtrans(const bf16* __restrict__ QKVb,
                                              bf16* __restrict__ Vtp) {
  __shared__ __align__(16) bf16 T[64 * 136];
  const int kvh = blockIdx.y;
  const int s0 = blockIdx.x * 64;   // one 64-key tile
  const int tid = threadIdx.x;
  for (int g = tid; g < 1024; g += 256) {
    int s = g >> 4, cg = g & 15;
    *(bf16x8*)(T + s * 136 + cg * 8) =
        *(const bf16x8*)(QKVb + (size_t)(s0 + s) * 4096 + 3072 + kvh * 128 + cg * 8);
  }
  __syncthreads();
  for (int g = tid; g < 1024; g += 256) {
    int d = g >> 3, sg = g & 7;
    bf16x8 v;
#pragma unroll
    for (int j = 0; j < 8; j++) {
      int kp = sg * 8 + j;
      int s = (kp & 3) * 16 + (kp >> 2);
      v[j] = T[s * 136 + d];
    }
    *(bf16x8*)(Vtp + ((size_t)kvh * 128 + d) * 4096 + s0 + sg * 8) = v;
  }
}

// ---------------------------------------------------------------------------
// Sliding-window GQA flash attention (unchanged this round).
// ---------------------------------------------------------------------------
__global__ __launch_bounds__(256, 2) void attn_kernel(const bf16* __restrict__ Qb,
                                                      const bf16* __restrict__ Kb,
                                                      const bf16* __restrict__ Vtp,
                                                      bf16* __restrict__ Ob) {
  const int SEQ = 4096, W = 1024;
  const float MP = 17.312340f;  // 12 * log2(e)
  __shared__ __align__(16) bf16 Ks[64 * 128];    // [key][d granule xor-swizzled]
  __shared__ __align__(16) bf16 Vs[128 * 64];    // [d][kp granule xor-swizzled]
  __shared__ __align__(16) bf16 Ps[4][32 * 64];  // per-wave P, xor-swizzled

  const int id = blockIdx.x;
  const int kvh = id & 7, gq = (id >> 3) & 1, h = kvh * 2 + gq;
  const int qb0 = (id >> 4) * 128;
  const int tid = threadIdx.x, w = tid >> 6, lane = tid & 63;
  const int l15 = lane & 15, quad = lane >> 4;
  const int qw0 = qb0 + w * 32;

  bf16x8 qf[2][4];
#pragma unroll
  for (int m = 0; m < 2; m++) {
    const bf16* qp = Qb + ((size_t)h * SEQ + qw0 + m * 16 + l15) * 128 + quad * 8;
#pragma unroll
    for (int kb = 0; kb < 4; kb++) qf[m][kb] = *(const bf16x8*)(qp + kb * 32);
  }

  f32x4 o[2][8] = {};
  f32x4 lr[2] = {};
  bf16* pw = &Ps[w][0];
  const bf16* kbase = Kb + (size_t)kvh * SEQ * 128;
  const bf16* vbase = Vtp + (size_t)kvh * 128 * SEQ;

  int jmin = qb0 - (W - 1); if (jmin < 0) jmin = 0;
  const int kt0 = jmin >> 6, kt1 = (qb0 + 127) >> 6;

  for (int kt = kt0; kt <= kt1; ++kt) {
    const int k0 = kt * 64;
#pragma unroll
    for (int i = 0; i < 4; i++) {
      int slot = w * 256 + i * 64 + lane;
      int key = slot >> 4, gg = slot & 15;
      int gsw = gg ^ (key & 7);
      gload_lds16(kbase + (size_t)(k0 + key) * 128 + gsw * 8, Ks + (w * 256 + i * 64) * 8);
    }
#pragma unroll
    for (int i = 0; i < 4; i++) {
      int slot = w * 256 + i * 64 + lane;
      int d = slot >> 3, gg = slot & 7;
      int gsw = gg ^ (d & 7);
      gload_lds16(vbase + (size_t)d * SEQ + k0 + gsw * 8, Vs + (w * 256 + i * 64) * 8);
    }
    __syncthreads();

    const bool alive = (k0 <= qw0 + 31) && (k0 + 63 > qw0 - W);
    if (alive) {
      const bool full = (k0 + 63 <= qw0) && (k0 > qw0 + 31 - W);
      f32x4 s[2][4] = {};
#pragma unroll
      for (int c = 0; c < 4; c++) {
        const int key = c * 16 + l15;
        bf16x8 kf[4];
#pragma unroll
        for (int kb = 0; kb < 4; kb++)
          kf[kb] = *(const bf16x8*)(Ks + key * 128 + (((kb * 4 + quad) ^ (key & 7)) << 3));
#pragma unroll
        for (int kb = 0; kb < 4; kb++) {
          s[0][c] = MFMA16(qf[0][kb], kf[kb], s[0][c]);
          s[1][c] = MFMA16(qf[1][kb], kf[kb], s[1][c]);
        }
      }
#pragma unroll
      for (int m = 0; m < 2; m++)
#pragma unroll
        for (int r = 0; r < 4; r++) {
          float p[4];
          if (full) {
#pragma unroll
            for (int c = 0; c < 4; c++) p[c] = __builtin_amdgcn_exp2f(s[m][c][r] - MP);
          } else {
            const int i_ = qw0 + m * 16 + quad * 4 + r;
#pragma unroll
            for (int c = 0; c < 4; c++) {
              int j = k0 + c * 16 + l15;
              p[c] = (j <= i_ && j > i_ - W) ? __builtin_amdgcn_exp2f(s[m][c][r] - MP) : 0.0f;
            }
          }
          lr[m][r] += p[0] + p[1] + p[2] + p[3];
          bf16x4 pk;
          pk[0] = (bf16)p[0]; pk[1] = (bf16)p[1]; pk[2] = (bf16)p[2]; pk[3] = (bf16)p[3];
          const int qrow = m * 16 + quad * 4 + r;
          *(bf16x4*)(pw + qrow * 64 + (((l15 >> 1) ^ (qrow & 7)) << 3) + (l15 & 1) * 4) = pk;
        }
      asm volatile("s_waitcnt lgkmcnt(0)" ::: "memory");
      bf16x8 pf[2][2];
#pragma unroll
      for (int m = 0; m < 2; m++)
#pragma unroll
        for (int kb = 0; kb < 2; kb++)
          pf[m][kb] = *(const bf16x8*)(pw + (m * 16 + l15) * 64 +
                                       (((kb * 4 + quad) ^ (l15 & 7)) << 3));
#pragma unroll
      for (int n = 0; n < 8; n++) {
        const int d = n * 16 + l15;
        bf16x8 vf0 = *(const bf16x8*)(Vs + d * 64 + ((quad ^ (l15 & 7)) << 3));
        bf16x8 vf1 = *(const bf16x8*)(Vs + d * 64 + (((4 + quad) ^ (l15 & 7)) << 3));
        o[0][n] = MFMA16(pf[0][0], vf0, o[0][n]);
        o[0][n] = MFMA16(pf[0][1], vf1, o[0][n]);
        o[1][n] = MFMA16(pf[1][0], vf0, o[1][n]);
        o[1][n] = MFMA16(pf[1][1], vf1, o[1][n]);
      }
    }
    __syncthreads();
  }

  float linv[2][4];
#pragma unroll
  for (int m = 0; m < 2; m++)
#pragma unroll
    for (int r = 0; r < 4; r++) {
      float v = lr[m][r];
      v += __shfl_xor(v, 1, 64);
      v += __shfl_xor(v, 2, 64);
      v += __shfl_xor(v, 4, 64);
      v += __shfl_xor(v, 8, 64);
      linv[m][r] = 1.0f / v;
    }
#pragma unroll
  for (int m = 0; m < 2; m++)
#pragma unroll
    for (int n = 0; n < 8; n++)
#pragma unroll
      for (int r = 0; r < 4; r++) {
        int i_ = qw0 + m * 16 + quad * 4 + r;
        Ob[(size_t)i_ * 2048 + h * 128 + n * 16 + l15] = (bf16)(o[m][n][r] * linv[m][r]);
      }
}

// ---------------------------------------------------------------------------
// Orchestration
// ---------------------------------------------------------------------------
extern "C" void kernel_launch(void* const* d_in, const int* in_sizes, int n_in,
                              void* d_out, int out_size, void* d_ws, size_t ws_size,
                              hipStream_t stream) {
  const float* hid  = (const float*)d_in[0];
  const float* cosb = (const float*)d_in[1];
  const float* sinb = (const float*)d_in[2];
  const float* Wq   = (const float*)d_in[3];
  const float* Wk   = (const float*)d_in[4];
  const float* Wv   = (const float*)d_in[5];
  const float* Wo   = (const float*)d_in[6];
  const float* qw   = (const float*)d_in[7];
  const float* kw   = (const float*)d_in[8];

  if (ws_size < (size_t)(112u) * 1024u * 1024u) return;

  char* ws = (char*)d_ws;
  bf16* Xbf  = (bf16*)(ws);                         // 4096x2048 (16 MB); slot
  bf16* Vtp  = (bf16*)(ws);                         //   reused for Vtp after gemm1
  bf16* Wcat = (bf16*)(ws + (16u << 20));           // [Wq;Wk;Wv] 4096x2048
  bf16* Wob  = (bf16*)(ws + (32u << 20));           // 2048x2048 (8 MB)
  bf16* QKVb = (bf16*)(ws + (40u << 20));           // 4096x4096 (32 MB)
  bf16* Qb   = (bf16*)(ws + (72u << 20));           // [16][4096][128] (16 MB)
  bf16* Kb   = (bf16*)(ws + (88u << 20));           // [8][4096][128] (8 MB)
  bf16* Ob   = (bf16*)(ws + (96u << 20));           // 4096x2048 (16 MB)

  cvt_f32_bf16<<<8192, 256, 0, stream>>>(hid, Xbf, 2097152);
  cvt_f32_bf16<<<4096, 256, 0, stream>>>(Wq, Wcat, 1048576);
  cvt_f32_bf16<<<2048, 256, 0, stream>>>(Wk, Wcat + 4194304, 524288);
  cvt_f32_bf16<<<2048, 256, 0, stream>>>(Wv, Wcat + 6291456, 524288);
  cvt_f32_bf16<<<4096, 256, 0, stream>>>(Wo, Wob, 1048576);

  gemm_pipe<256, 256, 8, 4, bf16><<<256, 512, 0, stream>>>(Xbf, Wcat, QKVb, 4096, 4096, 2048);
  vtrans<<<dim3(64, 8), 256, 0, stream>>>(QKVb, Vtp);   // Xbf dead after gemm1
  normrope<<<24576, 256, 0, stream>>>(QKVb, cosb, sinb, qw, kw, Qb, Kb);
  attn_kernel<<<512, 256, 0, stream>>>(Qb, Kb, Vtp, Ob);
  gemm_pipe<128, 256, 4, 4, float><<<256, 512, 0, stream>>>(Ob, Wob, (float*)d_out, 4096, 2048, 2048);
}